// Round 9
// baseline (528.162 us; speedup 1.0000x reference)
//
#include <hip/hip_runtime.h>
#include <hip/hip_bf16.h>
#include <stdint.h>

typedef __hip_bfloat16 bf16;
typedef __attribute__((ext_vector_type(8))) short short8;
typedef __attribute__((ext_vector_type(4))) short short4_t;
typedef __attribute__((ext_vector_type(4))) float float4_t;

__device__ __forceinline__ short f2b_bits(float f) {
  union { float f; unsigned u; } v; v.f = f;
  unsigned r = (v.u + 0x7FFF + ((v.u >> 16) & 1)) >> 16;  // RNE
  return (short)r;
}
__device__ __forceinline__ bf16 f2b(float f) {
  short s = f2b_bits(f);
  bf16 h; __builtin_memcpy(&h, &s, 2);
  return h;
}
// load element idx from p (fp32 if f32 else bf16) -> bf16
__device__ __forceinline__ bf16 ld_bf16(const void* p, size_t idx, int f32) {
  if (f32) return f2b(((const float*)p)[idx]);
  return ((const bf16*)p)[idx];
}

// async global->LDS, 16B per lane. LDS dest must be wave-uniform base + lane*16.
__device__ __forceinline__ void gload_lds16(const void* g, void* l) {
  __builtin_amdgcn_global_load_lds(
      (const __attribute__((address_space(1))) void*)g,
      (__attribute__((address_space(3))) void*)l, 16, 0, 0);
}

// ---------- dtype detector: probe = bi (1024 elements) ----------
__global__ void detect_dtype(const void* probe, int* flag) {
  int lane = threadIdx.x;  // 64 threads
  const unsigned short* u = (const unsigned short*)probe;
  const float* fp = (const float*)probe;
  int cb = 0, cf = 0;
  for (int j = lane; j < 256; j += 64) {
    unsigned short he = u[2 * j];
    int e = (he >> 7) & 0xFF;
    cb += (e >= 0x60 && e <= 0x7E);
    float af = fabsf(fp[j]);
    cf += (af > 1e-9f && af < 1.0f);
  }
#pragma unroll
  for (int off = 32; off > 0; off >>= 1) {
    cb += __shfl_down(cb, off);
    cf += __shfl_down(cf, off);
  }
  if (lane == 0) *flag = (cf > cb) ? 1 : 0;  // 1 = inputs are fp32
}

// ---------- bulk convert x -> bf16 (copy if already bf16) ----------
__global__ __launch_bounds__(256) void cvt_x(const void* __restrict__ x,
                                             bf16* __restrict__ xb,
                                             const int* __restrict__ flagp,
                                             size_t n) {
  const int f32 = *flagp;
  size_t i = ((size_t)blockIdx.x * 256 + threadIdx.x) * 8;
  size_t stride = (size_t)gridDim.x * 256 * 8;
  for (; i < n; i += stride) {
    if (f32) {
      const float* xp = (const float*)x + i;
      float4_t f0 = *(const float4_t*)xp;
      float4_t f1 = *(const float4_t*)(xp + 4);
      short8 v;
      v[0] = f2b_bits(f0[0]); v[1] = f2b_bits(f0[1]);
      v[2] = f2b_bits(f0[2]); v[3] = f2b_bits(f0[3]);
      v[4] = f2b_bits(f1[0]); v[5] = f2b_bits(f1[1]);
      v[6] = f2b_bits(f1[2]); v[7] = f2b_bits(f1[3]);
      *(short8*)(xb + i) = v;
    } else {
      *(short8*)(xb + i) = *(const short8*)((const bf16*)x + i);
    }
  }
}

// ---------- all 4 weight transposes in ONE launch (range-decoded) ----------
__global__ __launch_bounds__(256) void transpose_all(
    const void* __restrict__ Wi, const void* __restrict__ Wb,
    const void* __restrict__ Wf, const void* __restrict__ Wo,
    bf16* __restrict__ WiT, bf16* __restrict__ WbfT2, bf16* __restrict__ WoT,
    const int* __restrict__ flagp)
{
  const int f32 = *flagp;
  int b = blockIdx.x;
  const void* src; bf16* dst; int K, N, tb;
  if (b < 1024)      { src = Wi; dst = WiT;              K = 4096; N = 1024; tb = b; }
  else if (b < 1152) { src = Wb; dst = WbfT2;            K = 1024; N = 512;  tb = b - 1024; }
  else if (b < 1280) { src = Wf; dst = WbfT2 + 512*1024; K = 1024; N = 512;  tb = b - 1152; }
  else               { src = Wo; dst = WoT;              K = 128;  N = 4096; tb = b - 1280; }
  int nbk = K >> 6;
  int kb = (tb % nbk) * 64, nb = (tb / nbk) * 64;
  __shared__ bf16 tile[64][65];
  int tx = threadIdx.x & 63;
  int ty = threadIdx.x >> 6;  // 0..3
#pragma unroll
  for (int i = 0; i < 64; i += 4)
    tile[ty + i][tx] = ld_bf16(src, (size_t)(kb + ty + i) * N + nb + tx, f32);
  __syncthreads();
#pragma unroll
  for (int i = 0; i < 64; i += 4)
    dst[(size_t)(nb + ty + i) * K + kb + tx] = tile[tx][ty + i];
}

// ---------- small conversions + Ww fused into WbfT2 rows 1024..1151 ----------
__global__ __launch_bounds__(256) void cvt_small(
    const void* __restrict__ Ww, const void* __restrict__ bw,
    const void* __restrict__ bi, const void* __restrict__ bb,
    const void* __restrict__ bf_, const void* __restrict__ bo,
    bf16* __restrict__ WbfT2, bf16* __restrict__ bbf2,
    bf16* __restrict__ biC, bf16* __restrict__ boC,
    const int* __restrict__ flagp)
{
  const int f32 = *flagp;
  int i = blockIdx.x * 256 + threadIdx.x;  // grid 512 -> 131072 threads
  if (i < 131072) {
    int r = i >> 10, k = i & 1023;
    bf16 v = (r < 8) ? ld_bf16(Ww, (size_t)k * 8 + r, f32) : f2b(0.f);
    WbfT2[(size_t)(1024 + r) * 1024 + k] = v;
  }
  if (i < 128) bbf2[1024 + i] = (i < 8) ? ld_bf16(bw, i, f32) : f2b(0.f);
  if (i < 1024) biC[i] = ld_bf16(bi, i, f32);
  if (i < 512)  bbf2[i] = ld_bf16(bb, i, f32);
  if (i < 512)  bbf2[512 + i] = ld_bf16(bf_, i, f32);
  if (i < 4096) boC[i] = ld_bf16(bo, i, f32);
}

// ---------- coalesced epilogue (shared by both cores) ----------
// MFMA C/D layout: col=lane&15, row=(lane>>4)*4+r. Stage per 64-col half in
// LDS, read back with lanes contiguous WITHIN one instruction (R8 fix).
__device__ __forceinline__ void epilogue_64x128(
    char* smem, float4_t (&acc)[2][4], const bf16* bias, const void* resid,
    void* C, int rf32, int cf32, int m0, int n0, int N, int clip_cols,
    int tid, int lane, int wm, int wn, int lm)
{
  float* EP = (float*)smem;           // [64][68] fp32 = 17408 B
  const int ep_c = (tid & 15) * 4;
#pragma unroll
  for (int h = 0; h < 2; h++) {
    if ((wn >> 6) == h) {
#pragma unroll
      for (int mi = 0; mi < 2; mi++)
#pragma unroll
        for (int ni = 0; ni < 4; ni++) {
          int cl = (wn - h * 64) + ni * 16 + lm;
#pragma unroll
          for (int r = 0; r < 4; r++) {
            int rw = wm + mi * 16 + (lane >> 4) * 4 + r;
            EP[rw * 68 + cl] = acc[mi][ni][r];
          }
        }
    }
    __syncthreads();
#pragma unroll
    for (int i = 0; i < 4; i++) {
      int rw  = (tid >> 4) + 16 * i;
      int gr  = m0 + rw;
      int col = n0 + h * 64 + ep_c;
      size_t idx = (size_t)gr * N + col;
      float4_t v = *(const float4_t*)(EP + rw * 68 + ep_c);
      float o[4];
#pragma unroll
      for (int j = 0; j < 4; j++) {
        float t = v[j] + __bfloat162float(bias[col + j]);
        if (col + j < clip_cols) t = fminf(fmaxf(t, -10.f), 10.f);
        o[j] = t;
      }
      if (resid) {
        if (rf32) {
          float4_t rv = *(const float4_t*)((const float*)resid + idx);
#pragma unroll
          for (int j = 0; j < 4; j++) o[j] += rv[j];
        } else {
          short4_t rv = *(const short4_t*)((const bf16*)resid + idx);
#pragma unroll
          for (int j = 0; j < 4; j++) {
            bf16 hb; short sb = rv[j]; __builtin_memcpy(&hb, &sb, 2);
            o[j] += __bfloat162float(hb);
          }
        }
      }
      if (cf32) {
        *(float4_t*)((float*)C + idx) = (float4_t){o[0], o[1], o[2], o[3]};
      } else {
        short4_t pv;
#pragma unroll
        for (int j = 0; j < 4; j++) pv[j] = f2b_bits(o[j]);
        *(short4_t*)((bf16*)C + idx) = pv;
      }
    }
    __syncthreads();
  }
}

// ---------- dbuf GEMM core (bf16 A): counted-vmcnt 2-phase pipeline ----------
// T3-min + T4 (catalog): double-buffered LDS, stage(t+1) issued before
// compute(t), RAW barriers (no __syncthreads drain), explicit
// s_waitcnt vmcnt(6) = loads/stage so prefetch stays in flight across
// barriers. vmcnt(0) only on the last K-step. R3's dbuf failed because it
// kept the full drain; this is the counted version (m218: counted-vs-drain0
// = +38-73%; m230/m248: 2-phase-counted ~ 92% of 8-phase).
__device__ __forceinline__ void gemm_core_db(
    const bf16* __restrict__ A,      // M x K bf16
    const bf16* __restrict__ BT,     // N x K bf16
    const bf16* __restrict__ bias,   // N
    const void* __restrict__ resid,  // nullable
    void* __restrict__ C,
    const int* __restrict__ rF32, const int* __restrict__ cF32,
    int M, int N, int K, int clip_cols)
{
  constexpr int BM = 64, BN = 128;
  __shared__ alignas(16) char smem[2 * (BM + BN) * 64 * 2];  // 49152 B
  bf16* As0 = (bf16*)smem;                    // 8 KB
  bf16* As1 = (bf16*)(smem + 16384 / 2);      // As1 at +8KB
  bf16* Bs0 = (bf16*)(smem + 16384);          // 16 KB
  bf16* Bs1 = (bf16*)(smem + 16384 + 16384);  // 16 KB
  const int rf32 = rF32 ? *rF32 : 0;
  const int cf32 = cF32 ? *cF32 : 0;
  const int tid  = threadIdx.x;
  const int wave = tid >> 6;
  const int lane = tid & 63;
  const int m0 = blockIdx.x * BM;
  const int n0 = blockIdx.y * BN;
  const int wm = (wave >> 1) * (BM / 2);
  const int wn = (wave & 1) * (BN / 2);
  const int lm = lane & 15;
  const int lk = (lane >> 4) * 8;

  auto stage = [&](bf16* as, bf16* bs, int k0) {
#pragma unroll
    for (int i = 0; i < BN / 32; i++) {   // 4 loads
      int V = tid + 256 * i;
      gload_lds16(BT + (size_t)(n0 + (V >> 3)) * K + k0 + (V & 7) * 8,
                  bs + (size_t)V * 8);
    }
#pragma unroll
    for (int i = 0; i < BM / 32; i++) {   // 2 loads
      int V = tid + 256 * i;
      gload_lds16(A + (size_t)(m0 + (V >> 3)) * K + k0 + (V & 7) * 8,
                  as + (size_t)V * 8);
    }
  };

  float4_t acc[2][4];
#pragma unroll
  for (int i = 0; i < 2; i++)
#pragma unroll
    for (int j = 0; j < 4; j++) acc[i][j] = (float4_t){0.f, 0.f, 0.f, 0.f};

  const int NT = K >> 6;
  stage(As0, Bs0, 0);                      // 6 loads in flight

  for (int t = 0; t < NT; t++) {
    bf16* Asc = (t & 1) ? As1 : As0;
    bf16* Bsc = (t & 1) ? Bs1 : Bs0;
    if (t + 1 < NT) {
      stage((t & 1) ? As0 : As1, (t & 1) ? Bs0 : Bs1, (t + 1) << 6);
      // 12 outstanding; wait to 6 -> stage(t) landed, stage(t+1) in flight
      asm volatile("s_waitcnt vmcnt(6)" ::: "memory");
    } else {
      asm volatile("s_waitcnt vmcnt(0)" ::: "memory");
    }
    __builtin_amdgcn_sched_barrier(0);
    __builtin_amdgcn_s_barrier();          // all waves: buf(t) ready
    __builtin_amdgcn_sched_barrier(0);
#pragma unroll
    for (int kk = 0; kk < 64; kk += 32) {
      short8 af[2], bfr[4];
#pragma unroll
      for (int mi = 0; mi < 2; mi++)
        af[mi] = *(const short8*)(Asc + (wm + mi * 16 + lm) * 64 + kk + lk);
#pragma unroll
      for (int ni = 0; ni < 4; ni++)
        bfr[ni] = *(const short8*)(Bsc + (wn + ni * 16 + lm) * 64 + kk + lk);
#pragma unroll
      for (int mi = 0; mi < 2; mi++)
#pragma unroll
        for (int ni = 0; ni < 4; ni++)
          acc[mi][ni] = __builtin_amdgcn_mfma_f32_16x16x32_bf16(
              af[mi], bfr[ni], acc[mi][ni], 0, 0, 0);
    }
    __builtin_amdgcn_sched_barrier(0);
    __builtin_amdgcn_s_barrier();          // reads of buf(t) done before overwrite
  }
  epilogue_64x128(smem, acc, bias, resid, C, rf32, cf32,
                  m0, n0, N, clip_cols, tid, lane, wm, wn, lm);
}

// ---------- single-buffer fallback core (fp32-or-bf16 A), R8 structure ------
__device__ __forceinline__ void gemm_core_sb(
    const void* __restrict__ A, const bf16* __restrict__ BT,
    const bf16* __restrict__ bias, const void* __restrict__ resid,
    void* __restrict__ C, const int* __restrict__ aF32,
    const int* __restrict__ rF32, const int* __restrict__ cF32,
    int M, int N, int K, int clip_cols)
{
  constexpr int BM = 64, BN = 128;
  __shared__ alignas(16) char smem[(BM + BN) * 64 * 2];
  bf16* As = (bf16*)smem;
  bf16* Bs = (bf16*)smem + BM * 64;
  const int af32 = aF32 ? *aF32 : 0;
  const int rf32 = rF32 ? *rF32 : 0;
  const int cf32 = cF32 ? *cF32 : 0;
  const int tid  = threadIdx.x;
  const int wave = tid >> 6;
  const int lane = tid & 63;
  const int m0 = blockIdx.x * BM;
  const int n0 = blockIdx.y * BN;
  const int wm = (wave >> 1) * (BM / 2);
  const int wn = (wave & 1) * (BN / 2);
  const int lm = lane & 15;
  const int lk = (lane >> 4) * 8;

  float4_t acc[2][4];
#pragma unroll
  for (int i = 0; i < 2; i++)
#pragma unroll
    for (int j = 0; j < 4; j++) acc[i][j] = (float4_t){0.f, 0.f, 0.f, 0.f};

  for (int k0 = 0; k0 < K; k0 += 64) {
#pragma unroll
    for (int i = 0; i < BN / 32; i++) {
      int V = tid + 256 * i;
      gload_lds16(BT + (size_t)(n0 + (V >> 3)) * K + k0 + (V & 7) * 8,
                  Bs + (size_t)V * 8);
    }
#pragma unroll
    for (int i = 0; i < BM / 32; i++) {
      int V = tid + 256 * i;
      int row = V >> 3, kc = (V & 7) * 8;
      if (af32) {
        const float* ap = (const float*)A + (size_t)(m0 + row) * K + k0 + kc;
        float4_t f0 = *(const float4_t*)ap;
        float4_t f1 = *(const float4_t*)(ap + 4);
        short8 v;
        v[0] = f2b_bits(f0[0]); v[1] = f2b_bits(f0[1]);
        v[2] = f2b_bits(f0[2]); v[3] = f2b_bits(f0[3]);
        v[4] = f2b_bits(f1[0]); v[5] = f2b_bits(f1[1]);
        v[6] = f2b_bits(f1[2]); v[7] = f2b_bits(f1[3]);
        *(short8*)(As + (size_t)V * 8) = v;
      } else {
        gload_lds16((const bf16*)A + (size_t)(m0 + row) * K + k0 + kc,
                    As + (size_t)V * 8);
      }
    }
    __syncthreads();
#pragma unroll
    for (int kk = 0; kk < 64; kk += 32) {
      short8 af[2], bfr[4];
#pragma unroll
      for (int mi = 0; mi < 2; mi++)
        af[mi] = *(const short8*)(As + (wm + mi * 16 + lm) * 64 + kk + lk);
#pragma unroll
      for (int ni = 0; ni < 4; ni++)
        bfr[ni] = *(const short8*)(Bs + (wn + ni * 16 + lm) * 64 + kk + lk);
#pragma unroll
      for (int mi = 0; mi < 2; mi++)
#pragma unroll
        for (int ni = 0; ni < 4; ni++)
          acc[mi][ni] = __builtin_amdgcn_mfma_f32_16x16x32_bf16(
              af[mi], bfr[ni], acc[mi][ni], 0, 0, 0);
    }
    __syncthreads();
  }
  epilogue_64x128(smem, acc, bias, resid, C, rf32, cf32,
                  m0, n0, N, clip_cols, tid, lane, wm, wn, lm);
}

// distinct names -> per-GEMM rocprof attribution
__global__ __launch_bounds__(256) void gemm_x(
    const bf16* A, const bf16* BT, const bf16* bias, const void* resid,
    void* C, const int* rF32, const int* cF32, int M, int N, int K, int clip_cols) {
  gemm_core_db(A, BT, bias, resid, C, rF32, cF32, M, N, K, clip_cols);
}
__global__ __launch_bounds__(256) void gemm_x_f(
    const void* A, const bf16* BT, const bf16* bias, const void* resid,
    void* C, const int* aF32, const int* rF32, const int* cF32,
    int M, int N, int K, int clip_cols) {
  gemm_core_sb(A, BT, bias, resid, C, aF32, rF32, cF32, M, N, K, clip_cols);
}
__global__ __launch_bounds__(256) void gemm_h(
    const bf16* A, const bf16* BT, const bf16* bias, const void* resid,
    void* C, const int* rF32, const int* cF32, int M, int N, int K, int clip_cols) {
  gemm_core_db(A, BT, bias, resid, C, rF32, cF32, M, N, K, clip_cols);
}
__global__ __launch_bounds__(256) void gemm_o(
    const bf16* A, const bf16* BT, const bf16* bias, const void* resid,
    void* C, const int* rF32, const int* cF32, int M, int N, int K, int clip_cols) {
  gemm_core_db(A, BT, bias, resid, C, rF32, cF32, M, N, K, clip_cols);
}

// ---------- per-token: softmax over fused logit cols + temporal mix + agg ----
__global__ __launch_bounds__(128) void build_combined(
    const bf16* __restrict__ bcfs,  // 8192 x 1152
    bf16* __restrict__ comb)        // 8192 x 128
{
  int t = blockIdx.x;
  int tid = threadIdx.x;
  int tl = t & 2047;
  __shared__ float lg[8];
  __shared__ float w[8];
  if (tid < 8) lg[tid] = __bfloat162float(bcfs[(size_t)t * 1152 + 1024 + tid]);
  __syncthreads();
  if (tid < 8) {
    float mx = lg[0];
#pragma unroll
    for (int i = 1; i < 8; i++) mx = fmaxf(mx, lg[i]);
    float den = 0.f;
#pragma unroll
    for (int i = 0; i < 8; i++) den += expf(lg[i] - mx);
    w[tid] = expf(lg[tid] - mx) / den;
  }
  __syncthreads();
  float s = 0.f;
  if (tid < 64) {
    int d = tid;
    const bf16* bc = bcfs + (size_t)t * 1152;
    size_t tp = (tl == 0) ? (size_t)t : (size_t)t - 1;
    const bf16* bp = bcfs + tp * 1152;
#pragma unroll
    for (int p = 0; p < 8; p++) {
      float cur = __bfloat162float(bc[p * 64 + d]);
      float v = (tl == 0) ? cur : (0.9f * cur + 0.1f * __bfloat162float(bp[p * 64 + d]));
      s += w[p] * v;
    }
  } else {
    int d = tid - 64;
    const bf16* fsrow = bcfs + (size_t)t * 1152 + 512;
#pragma unroll
    for (int p = 0; p < 8; p++) s += w[p] * __bfloat162float(fsrow[p * 64 + d]);
  }
  comb[(size_t)t * 128 + tid] = __float2bfloat16(s);
}

extern "C" void kernel_launch(void* const* d_in, const int* in_sizes, int n_in,
                              void* d_out, int out_size, void* d_ws, size_t ws_size,
                              hipStream_t stream) {
  (void)in_sizes; (void)n_in; (void)out_size;
  const void* x   = d_in[0];   // 8192 x 4096
  const void* Wi  = d_in[1];   // 4096 x 1024
  const void* bi  = d_in[2];   // 1024
  const void* Wb  = d_in[3];   // 1024 x 512
  const void* bb  = d_in[4];   // 512
  const void* Wf  = d_in[5];   // 1024 x 512
  const void* bfv = d_in[6];   // 512
  const void* Ww  = d_in[9];   // 1024 x 8
  const void* bw  = d_in[10];  // 8
  const void* Wo  = d_in[17];  // 128 x 4096
  const void* bo  = d_in[18];  // 4096

  char* ws = (char*)d_ws;
  bf16*  h_bot = (bf16*)(ws + 0);          // 16,777,216 (comb aliases after GEMM2)
  bf16*  comb  = (bf16*)(ws + 0);
  bf16*  bcfs  = (bf16*)(ws + 16777216);   // 8192x1152x2 = 18,874,368
  bf16*  WiT   = (bf16*)(ws + 35651584);   //  8,388,608
  bf16*  WbfT2 = (bf16*)(ws + 44040192);   //  2,359,296
  bf16*  WoT   = (bf16*)(ws + 46399488);   //  1,048,576
  bf16*  biC   = (bf16*)(ws + 47448064);
  bf16*  bbf2C = (bf16*)(ws + 47450112);
  bf16*  boC   = (bf16*)(ws + 47452416);
  int*   flag  = (int*)(ws + 47460608);
  bf16*  xb    = (bf16*)(ws + 47464448);   // 67,108,864 (optional)
  const bool use_xb = ws_size >= (size_t)47464448 + 67108864;

  detect_dtype<<<1, 64, 0, stream>>>(bi, flag);

  if (use_xb)
    cvt_x<<<2048, 256, 0, stream>>>(x, xb, flag, (size_t)8192 * 4096);

  transpose_all<<<1408, 256, 0, stream>>>(Wi, Wb, Wf, Wo, WiT, WbfT2, WoT, flag);
  cvt_small<<<512, 256, 0, stream>>>(Ww, bw, bi, bb, bfv, bo,
                                     WbfT2, bbf2C, biC, boC, flag);

  // GEMM1: h_bot = x @ Wi + bi  (64x128, grid 1024; dbuf counted-vmcnt)
  if (use_xb)
    gemm_x<<<dim3(128, 8), 256, 0, stream>>>(
        xb, WiT, biC, nullptr, h_bot, nullptr, nullptr,
        8192, 1024, 4096, 0);
  else
    gemm_x_f<<<dim3(128, 8), 256, 0, stream>>>(
        x, WiT, biC, nullptr, h_bot, flag, nullptr, nullptr,
        8192, 1024, 4096, 0);
  // GEMM2: [bc | fs | logits | pad] = h_bot @ [Wb|Wf|Ww|0] + [bb|bf|bw|0]
  gemm_h<<<dim3(128, 9), 256, 0, stream>>>(
      h_bot, WbfT2, bbf2C, nullptr, bcfs, nullptr, nullptr,
      8192, 1152, 1024, 512);
  build_combined<<<8192, 128, 0, stream>>>(bcfs, comb);
  // GEMM3: out = x + comb @ Wo + bo — resid = x (flagged), OUTPUT dtype follows flag
  gemm_o<<<dim3(128, 32), 256, 0, stream>>>(
      comb, WoT, boC, x, d_out, flag, flag,
      8192, 4096, 128, 0);
}